// Round 5
// baseline (279.969 us; speedup 1.0000x reference)
//
#include <hip/hip_runtime.h>

// loss = sum((input - target)^2) / (N/4), by orthonormality of the 2x2 Haar
// transform. N = 4*32*512*512 = 33554432; divisor = N/4 = 8388608.
//
// Harness floor: ~170 us = d_ws 512MB fill (78us @6.9TB/s) + d_in restore.
// Controllable part = stage1 (+ tiny stage2), currently ~72us = 3.7 TB/s.
//
// R10 (this file): every register-load variant (burst-16, pipe-8, shallow
// +32waves/CU) pins at 3.5-3.7 TB/s read even though in-flight bytes exceed
// the Little's-law need by >10x, and LLC-resident replays are no faster
// with zero competing writes -> the ceiling is the per-CU VMEM->VGPR
// return/miss-queue path, not DRAM and not latency-hiding capacity.
// (Cross-check: m13 copy = only ~3.15 TB/s of reads; 6.9 TB/s fill is
// write-only.) The LDS-DMA path (global_load_lds) is the one mechanism
// with measured higher per-CU read throughput (m97 GEMM: ~53 GB/s/CU
// staged). Rewrite: per-wave-PRIVATE LDS double-buffer streaming, counted
// vmcnt(2) (never 0 mid-loop), zero __syncthreads. Same element->thread
// mapping as before -> bitwise-identical sums -> absmax 0.
// Grid 2048 = 8 blocks/CU exactly resident (persistent, no churn).
// Predicted: stage1 72 -> ~50us (total ~225) if DMA queue is deeper;
// unchanged (~248) if it shares the register-path queue -> roofline.

typedef float fvec4 __attribute__((ext_vector_type(4)));

#define S1_BLOCK  256
#define S1_ROUNDS 16
#define S1_RCHUNK S1_BLOCK                  // float4s per block per round (per tensor)
#define S1_CHUNK  (S1_RCHUNK * S1_ROUNDS)   // 4096 float4s per tensor per block

typedef const __attribute__((address_space(1))) void g_void;
typedef __attribute__((address_space(3))) void lds_void;

__global__ __launch_bounds__(S1_BLOCK, 8) void haar_mse_stage1(
    const fvec4* __restrict__ x,
    const fvec4* __restrict__ t,
    float* __restrict__ ws,
    int n4)
{
    __shared__ fvec4 bx[2][S1_BLOCK];
    __shared__ fvec4 bt[2][S1_BLOCK];

    const int tid  = threadIdx.x;
    const int wave = tid >> 6;
    const int lane = tid & 63;
    const int woff = wave << 6;             // this wave's float4 offset in a round
    const int cbase = blockIdx.x * S1_CHUNK;

    float acc0 = 0.0f, acc1 = 0.0f, acc2 = 0.0f, acc3 = 0.0f;

    if (cbase + S1_CHUNK <= n4) {
        // fast path (always taken for the bench shape).
        // Wave w stages its own 1KB slice of each tensor per round into its
        // own LDS slot (HW writes lds_base + lane*16; global src is per-lane)
        // and reads back only its own slot -> LDS is wave-private, no
        // s_barrier needed anywhere. Pipeline: while computing round r,
        // round r+1's 2KB is in flight; the counted vmcnt(2) waits only for
        // round r's two DMA instructions.
        const fvec4* gx = x + cbase + woff + lane;
        const fvec4* gt = t + cbase + woff + lane;

        // prologue: stage round 0 into buffer 0
        __builtin_amdgcn_global_load_lds((g_void*)gx, (lds_void*)&bx[0][woff], 16, 0, 0);
        __builtin_amdgcn_global_load_lds((g_void*)gt, (lds_void*)&bt[0][woff], 16, 0, 0);

        #pragma unroll
        for (int r = 0; r < S1_ROUNDS; ++r) {
            const int cur = r & 1;
            const int nxt = cur ^ 1;
            if (r + 1 < S1_ROUNDS) {
                __builtin_amdgcn_global_load_lds((g_void*)(gx + (r + 1) * S1_RCHUNK),
                                                 (lds_void*)&bx[nxt][woff], 16, 0, 0);
                __builtin_amdgcn_global_load_lds((g_void*)(gt + (r + 1) * S1_RCHUNK),
                                                 (lds_void*)&bt[nxt][woff], 16, 0, 0);
                // wait for round r's 2 DMAs; keep round r+1's 2 in flight
                asm volatile("s_waitcnt vmcnt(2)" ::: "memory");
            } else {
                asm volatile("s_waitcnt vmcnt(0)" ::: "memory");
            }
            __builtin_amdgcn_sched_barrier(0);

            fvec4 a = bx[cur][woff + lane];
            fvec4 b = bt[cur][woff + lane];
            fvec4 d = a - b;
            acc0 = fmaf(d.x, d.x, acc0);
            acc1 = fmaf(d.y, d.y, acc1);
            acc2 = fmaf(d.z, d.z, acc2);
            acc3 = fmaf(d.w, d.w, acc3);

            __builtin_amdgcn_sched_barrier(0);
        }
    } else {
        // tail path (not taken for the bench shape)
        const int end = (cbase + S1_CHUNK < n4) ? (cbase + S1_CHUNK) : n4;
        for (int i = cbase + tid; i < end; i += S1_BLOCK) {
            fvec4 a = x[i];
            fvec4 b = t[i];
            fvec4 d = a - b;
            acc0 = fmaf(d.x, d.x, acc0);
            acc1 = fmaf(d.y, d.y, acc1);
            acc2 = fmaf(d.z, d.z, acc2);
            acc3 = fmaf(d.w, d.w, acc3);
        }
    }

    float acc = (acc0 + acc1) + (acc2 + acc3);

    // wave (64-lane) shuffle reduction
    #pragma unroll
    for (int off = 32; off > 0; off >>= 1)
        acc += __shfl_down(acc, off, 64);

    __shared__ float wave_sums[4];
    if (lane == 0) wave_sums[wave] = acc;
    __syncthreads();

    if (tid == 0)
        ws[blockIdx.x] = (wave_sums[0] + wave_sums[1]) + (wave_sums[2] + wave_sums[3]);
}

__global__ __launch_bounds__(256) void haar_mse_stage2(
    const float* __restrict__ ws,
    float* __restrict__ out,
    int nblocks,
    float scale)
{
    float s = 0.0f;
    for (int i = threadIdx.x; i < nblocks; i += 256)
        s += ws[i];

    #pragma unroll
    for (int off = 32; off > 0; off >>= 1)
        s += __shfl_down(s, off, 64);

    __shared__ float wave_sums[4];
    const int wave = threadIdx.x >> 6;
    const int lane = threadIdx.x & 63;
    if (lane == 0) wave_sums[wave] = s;
    __syncthreads();

    if (threadIdx.x == 0)
        out[0] = ((wave_sums[0] + wave_sums[1]) + (wave_sums[2] + wave_sums[3])) * scale;
}

extern "C" void kernel_launch(void* const* d_in, const int* in_sizes, int n_in,
                              void* d_out, int out_size, void* d_ws, size_t ws_size,
                              hipStream_t stream) {
    const float* x = (const float*)d_in[0];
    const float* t = (const float*)d_in[1];
    float* out = (float*)d_out;
    float* ws  = (float*)d_ws;

    const int n  = in_sizes[0];   // 33554432
    const int n4 = n / 4;         // 8388608 float4s
    const int nblocks = (n4 + S1_CHUNK - 1) / S1_CHUNK;   // 2048

    haar_mse_stage1<<<nblocks, S1_BLOCK, 0, stream>>>(
        (const fvec4*)x, (const fvec4*)t, ws, n4);

    const float scale = 1.0f / (float)(n / 4);            // 1/8388608
    haar_mse_stage2<<<1, 256, 0, stream>>>(ws, out, nblocks, scale);
}

// Round 6
// 249.202 us; speedup vs baseline: 1.1235x; 1.1235x over previous
//
#include <hip/hip_runtime.h>

// loss = sum((input - target)^2) / (N/4), by orthonormality of the 2x2 Haar
// transform (sum of the 4 band MSEs == overall pixel SSE * 4/N).
// N = 4*32*512*512 = 33554432; divisor = N/4 = 8388608.
//
// Harness floor: ~163 us = d_ws 512MB fill (78us @6.9TB/s, write-only) +
// d_in restore (~85us). Controllable part = stage1 (+ tiny stage2).
//
// R11 (this file): REVERT to the best-measured variant (R8, 247.6us).
// Five structural probes (R6-R10) established the stage1 ceiling model:
// nt-load variants pin at 3.6-3.7 TB/s regardless of per-wave depth
// (2..16 float4 in flight), occupancy (16 vs 32 waves/CU), or destination
// (VGPR vs LDS-DMA, R10: worse, ~2.5 TB/s), and — decisively — regardless
// of data residency (R6/R10 rocprof replays served from LLC were no
// faster). The limiter is the per-CU read-return path: ~40ish outstanding
// 128B lines x ~375ns ~= 14-15 GB/s/CU x 256 CU ~= 3.7 TB/s. External
// corroboration: m13 float4 copy = 6.29 TB/s AGGREGATE (~3.15 TB/s reads);
// the 6.9 TB/s fill is write-only (posted writes don't use the return
// queue). Stage1 at 268MB / ~72us = 3.7 TB/s IS this chip's read roofline.
// Remaining non-floor slack (stage2 + 2 launch gaps, ~10us) is at the
// run-to-run noise level.

typedef float fvec4 __attribute__((ext_vector_type(4)));

#define S1_BLOCK   256
#define S1_DEPTH   4                    // float4s per batch per thread per tensor
#define S1_BATCHES 8                    // batches per thread
#define S1_CHUNK   (S1_BLOCK * S1_DEPTH * S1_BATCHES)   // 8192 float4s per tensor per block

__global__ __launch_bounds__(S1_BLOCK) void haar_mse_stage1(
    const fvec4* __restrict__ x,
    const fvec4* __restrict__ t,
    float* __restrict__ ws,
    int n4)
{
    const int tid  = threadIdx.x;
    const int base = blockIdx.x * S1_CHUNK + tid;

    float acc0 = 0.0f, acc1 = 0.0f, acc2 = 0.0f, acc3 = 0.0f;

    if (blockIdx.x * S1_CHUNK + S1_CHUNK <= n4) {
        // fast path (always taken for the bench shape):
        // double-buffered 2-deep pipeline; batch j+1's 8 nt loads are in
        // flight while batch j is consumed. Full unroll -> static indices.
        fvec4 a[2][S1_DEPTH], b[2][S1_DEPTH];

        // prologue: batch 0 into buffer 0
        #pragma unroll
        for (int k = 0; k < S1_DEPTH; ++k) {
            a[0][k] = __builtin_nontemporal_load(&x[base + k * S1_BLOCK]);
            b[0][k] = __builtin_nontemporal_load(&t[base + k * S1_BLOCK]);
        }

        #pragma unroll
        for (int j = 0; j < S1_BATCHES; ++j) {
            const int cur = j & 1;
            const int nxt = cur ^ 1;
            if (j + 1 < S1_BATCHES) {
                const int nb = base + (j + 1) * (S1_DEPTH * S1_BLOCK);
                #pragma unroll
                for (int k = 0; k < S1_DEPTH; ++k) {
                    a[nxt][k] = __builtin_nontemporal_load(&x[nb + k * S1_BLOCK]);
                    b[nxt][k] = __builtin_nontemporal_load(&t[nb + k * S1_BLOCK]);
                }
            }
            // keep the prefetch cluster above the compute (no sinking/hoisting)
            __builtin_amdgcn_sched_barrier(0);
            #pragma unroll
            for (int k = 0; k < S1_DEPTH; ++k) {
                fvec4 d = a[cur][k] - b[cur][k];
                acc0 = fmaf(d.x, d.x, acc0);
                acc1 = fmaf(d.y, d.y, acc1);
                acc2 = fmaf(d.z, d.z, acc2);
                acc3 = fmaf(d.w, d.w, acc3);
            }
        }
    } else {
        // tail path (not taken for the bench shape)
        for (int j = 0; j < S1_BATCHES; ++j) {
            for (int k = 0; k < S1_DEPTH; ++k) {
                const int i = base + j * (S1_DEPTH * S1_BLOCK) + k * S1_BLOCK;
                if (i < n4) {
                    fvec4 av = x[i];
                    fvec4 bv = t[i];
                    fvec4 d = av - bv;
                    acc0 = fmaf(d.x, d.x, acc0);
                    acc1 = fmaf(d.y, d.y, acc1);
                    acc2 = fmaf(d.z, d.z, acc2);
                    acc3 = fmaf(d.w, d.w, acc3);
                }
            }
        }
    }

    float acc = (acc0 + acc1) + (acc2 + acc3);

    // wave (64-lane) shuffle reduction
    #pragma unroll
    for (int off = 32; off > 0; off >>= 1)
        acc += __shfl_down(acc, off, 64);

    __shared__ float wave_sums[4];
    const int wave = tid >> 6;
    const int lane = tid & 63;
    if (lane == 0) wave_sums[wave] = acc;
    __syncthreads();

    if (tid == 0)
        ws[blockIdx.x] = (wave_sums[0] + wave_sums[1]) + (wave_sums[2] + wave_sums[3]);
}

__global__ __launch_bounds__(256) void haar_mse_stage2(
    const float* __restrict__ ws,
    float* __restrict__ out,
    int nblocks,
    float scale)
{
    float s = 0.0f;
    for (int i = threadIdx.x; i < nblocks; i += 256)
        s += ws[i];

    #pragma unroll
    for (int off = 32; off > 0; off >>= 1)
        s += __shfl_down(s, off, 64);

    __shared__ float wave_sums[4];
    const int wave = threadIdx.x >> 6;
    const int lane = threadIdx.x & 63;
    if (lane == 0) wave_sums[wave] = s;
    __syncthreads();

    if (threadIdx.x == 0)
        out[0] = ((wave_sums[0] + wave_sums[1]) + (wave_sums[2] + wave_sums[3])) * scale;
}

extern "C" void kernel_launch(void* const* d_in, const int* in_sizes, int n_in,
                              void* d_out, int out_size, void* d_ws, size_t ws_size,
                              hipStream_t stream) {
    const float* x = (const float*)d_in[0];
    const float* t = (const float*)d_in[1];
    float* out = (float*)d_out;
    float* ws  = (float*)d_ws;

    const int n  = in_sizes[0];   // 33554432
    const int n4 = n / 4;         // 8388608 float4s
    const int nblocks = (n4 + S1_CHUNK - 1) / S1_CHUNK;   // 1024

    haar_mse_stage1<<<nblocks, S1_BLOCK, 0, stream>>>(
        (const fvec4*)x, (const fvec4*)t, ws, n4);

    const float scale = 1.0f / (float)(n / 4);            // 1/8388608
    haar_mse_stage2<<<1, 256, 0, stream>>>(ws, out, nblocks, scale);
}